// Round 14
// baseline (126.021 us; speedup 1.0000x reference)
//
#include <hip/hip_runtime.h>
#include <cmath>

// MHSA cosine-attention block, MI355X/gfx950.  Round 14.
// K1: QKV projection as MFMA GEMM, 16-l tiles -> 512 blocks (2/CU).
// K2: R8 structure (32-key chunks, K dbuf 8 KB, P 10 KB, V register
//     ping-pong) with __launch_bounds__(256, 6): VGPR measured 68 <= 85
//     cap, LDS 18 KB -> 6 blocks/CU (was 4).  Occupancy is the binding
//     resource (R13 profile: both pipes <31% busy at 2 blocks/CU).
// K3: vectorized bf16 partial reduce (R11).

typedef __bf16 bf16x8 __attribute__((ext_vector_type(8)));
typedef __bf16 bf16x4 __attribute__((ext_vector_type(4)));
typedef float f4_t __attribute__((ext_vector_type(4)));

#define LQ 4096       // sequence length H*W
#define NH 4          // n*heads
#define KS 8          // key splits

__device__ inline f4_t mfma16(bf16x8 a, bf16x8 b, f4_t c) {
    return __builtin_amdgcn_mfma_f32_16x16x32_bf16(a, b, c, 0, 0, 0);
}

__device__ inline bf16x8 cvt8(const float* p) {
    f4_t a = *(const f4_t*)p, b = *(const f4_t*)(p + 4);
    bf16x8 r;
    r[0] = (__bf16)a[0]; r[1] = (__bf16)a[1]; r[2] = (__bf16)a[2]; r[3] = (__bf16)a[3];
    r[4] = (__bf16)b[0]; r[5] = (__bf16)b[1]; r[6] = (__bf16)b[2]; r[7] = (__bf16)b[3];
    return r;
}

// ---------------------------------------------------------------------------
// Kernel 1: QKV projection + normalize via MFMA.
// grid: dim3(256, 2) = l-tile(16) x n = 512 blocks (2/CU).  block: 256 thr.
// ---------------------------------------------------------------------------
__global__ __launch_bounds__(256) void k1_qkv(
        const float* __restrict__ x,
        const float* __restrict__ Wq, const float* __restrict__ bq,
        const float* __restrict__ Wk, const float* __restrict__ bk,
        const float* __restrict__ Wv, const float* __restrict__ bv,
        __bf16* __restrict__ Qb, __bf16* __restrict__ Kb,
        __bf16* __restrict__ Vtb) {
    const int tid  = threadIdx.x;
    const int lane = tid & 63;
    const int w    = tid >> 6;
    const int quad = lane >> 4;
    const int l15  = lane & 15;
    const int lt   = blockIdx.x;
    const int n    = blockIdx.y;
    const int l0   = lt * 16;

    __shared__ __bf16 xl[16][72];   // [l][c] bf16, pitch 72

    {
        const int l = tid & 15, c0 = tid >> 4;
#pragma unroll
        for (int i = 0; i < 4; ++i) {
            const int c = c0 * 4 + i;
            xl[l][c] = (__bf16)x[((size_t)n * 64 + c) * LQ + l0 + l];
        }
    }

    const float* Wqk = (w < 2) ? Wq : Wk;
    const float* bqk = (w < 2) ? bq : bk;
    const int h = w & 1;

    bf16x8 af[4][2], av[2];
#pragma unroll
    for (int t = 0; t < 4; ++t)
#pragma unroll
        for (int kh = 0; kh < 2; ++kh)
            af[t][kh] = cvt8(Wqk + (size_t)(h * 64 + t * 16 + l15) * 64
                                  + kh * 32 + quad * 8);
#pragma unroll
    for (int kh = 0; kh < 2; ++kh)
        av[kh] = cvt8(Wv + (size_t)(w * 16 + l15) * 64 + kh * 32 + quad * 8);

    f4_t binit[4], bvinit;
#pragma unroll
    for (int t = 0; t < 4; ++t)
#pragma unroll
        for (int r = 0; r < 4; ++r)
            binit[t][r] = bqk[h * 64 + t * 16 + quad * 4 + r];
#pragma unroll
    for (int r = 0; r < 4; ++r)
        bvinit[r] = bv[w * 16 + quad * 4 + r];

    __syncthreads();

    f4_t acc[4], vacc;
    {
        bf16x8 bf0 = *(const bf16x8*)&xl[l15][quad * 8];
        bf16x8 bf1 = *(const bf16x8*)&xl[l15][32 + quad * 8];
#pragma unroll
        for (int t = 0; t < 4; ++t) {
            f4_t a = mfma16(af[t][0], bf0, binit[t]);
            acc[t] = mfma16(af[t][1], bf1, a);
        }
        f4_t va = mfma16(av[0], bf0, bvinit);
        vacc = mfma16(av[1], bf1, va);
    }

    const int nh = n * 2 + h;
    __bf16* dst  = (w < 2) ? Qb : Kb;
    const float post = (w < 2) ? 1.44269504f : 1.0f;
    {
        float ss = 0.f;
#pragma unroll
        for (int t = 0; t < 4; ++t)
#pragma unroll
            for (int r = 0; r < 4; ++r)
                ss = fmaf(acc[t][r], acc[t][r], ss);
        ss += __shfl_xor(ss, 16, 64);
        ss += __shfl_xor(ss, 32, 64);
        const float rn = post / fmaxf(sqrtf(ss), 1e-6f);

        const int l = l0 + l15;
#pragma unroll
        for (int t = 0; t < 4; ++t) {
            bf16x4 pk;
#pragma unroll
            for (int r = 0; r < 4; ++r) pk[r] = (__bf16)(acc[t][r] * rn);
            const int kc = t * 2 + (quad >> 1);
            *(bf16x4*)(dst + ((size_t)(nh * 8 + kc) * LQ + l) * 8 + (quad & 1) * 4) = pk;
        }
#pragma unroll
        for (int r = 0; r < 4; ++r) {
            const int vrow = w * 16 + quad * 4 + r;
            Vtb[(size_t)(n * 64 + vrow) * LQ + l] = (__bf16)vacc[r];
        }
    }
}

// ---------------------------------------------------------------------------
// Kernel 2: flash attention (R8 structure, occupancy-raised).
// grid: (32 q-blocks of 128, nh=4, ks=8) = 1024 blocks x 4 waves.
// 16 chunks x 32 keys; K dbuf 2x4 KB (shuffled conflict-free map);
// V register ping-pong; P same-wave LDS round trip.  LDS 18 KB +
// launch_bounds(256,6) -> 6 blocks/CU.
// ---------------------------------------------------------------------------
__global__ __launch_bounds__(256, 6) void k2_attn(
        const __bf16* __restrict__ Qb, const __bf16* __restrict__ Kb,
        const __bf16* __restrict__ Vtb,
        __bf16* __restrict__ numPb, float* __restrict__ denP) {
    const int tid  = threadIdx.x;
    const int lane = tid & 63;
    const int wave = tid >> 6;
    const int quad = lane >> 4;
    const int l15  = lane & 15;
    const int nh   = blockIdx.y;
    const int ks   = blockIdx.z;
    const int qbase = blockIdx.x * 128 + wave * 32;
    const int kbase = ks * 512;

    __shared__ __bf16 Kl[2][2048];       // 2 x 4 KB staged K chunks (32 keys)
    __shared__ __bf16 P[4][2][16][40];   // [wave][qt][q-row][32 keys + pad]

    const f4_t fzero = {0.f, 0.f, 0.f, 0.f};

    // staging slot map: slot t <-> (kc = ((t>>6)&1)*4 + ((t>>4)&3),
    //                              l  = ((t>>7)<<4)  | (t&15))
    const int s_kc = ((tid >> 6) & 1) * 4 + ((tid >> 4) & 3);
    const int s_l  = ((tid >> 7) << 4) | (tid & 15);
    const __bf16* s_src = Kb + ((size_t)(nh * 8 + s_kc) * LQ + kbase + s_l) * 8;

    // Q fragments (k8-tiled layout), reused for all 512 keys
    bf16x8 qf[2][2];
#pragma unroll
    for (int qt = 0; qt < 2; ++qt)
#pragma unroll
        for (int kh = 0; kh < 2; ++kh)
            qf[qt][kh] = *(const bf16x8*)(Qb +
                ((size_t)(nh * 8 + kh * 4 + quad) * LQ + qbase + qt * 16 + l15) * 8);

    f4_t racc[2][2];                     // [vt][qt]
#pragma unroll
    for (int a = 0; a < 2; ++a)
#pragma unroll
        for (int b = 0; b < 2; ++b) racc[a][b] = fzero;
    float den[2] = {0.f, 0.f};

    // V source base (vt=0; vt=1 adds 16*LQ); chunk ch adds ch*32
    const __bf16* v_src = Vtb + (size_t)(nh * 32 + l15) * LQ + kbase + quad * 8;
    bf16x8 vf_cur0 = *(const bf16x8*)v_src;
    bf16x8 vf_cur1 = *(const bf16x8*)(v_src + (size_t)16 * LQ);

    // stage chunk 0 into buffer 0
    *(bf16x8*)&Kl[0][tid * 8] = *(const bf16x8*)s_src;
    __syncthreads();

#pragma unroll 2
    for (int ch = 0; ch < 16; ++ch) {
        const int cur = ch & 1;

        // prefetch next chunk: K -> LDS (other buffer), V -> registers
        bf16x8 vf_nxt0, vf_nxt1;
        if (ch < 15) {
            *(bf16x8*)&Kl[cur ^ 1][tid * 8] =
                *(const bf16x8*)(s_src + (size_t)(ch + 1) * 256);
            vf_nxt0 = *(const bf16x8*)(v_src + (ch + 1) * 32);
            vf_nxt1 = *(const bf16x8*)(v_src + (size_t)16 * LQ + (ch + 1) * 32);
        }

        // K fragments from staged LDS (contiguous 1 KB per wave-read)
        bf16x8 kf[2][2];
#pragma unroll
        for (int kt = 0; kt < 2; ++kt)
#pragma unroll
            for (int kh = 0; kh < 2; ++kh)
                kf[kt][kh] = *(const bf16x8*)
                    &Kl[cur][(kt * 128 + kh * 64 + quad * 16 + l15) * 8];

        // --- all S^T tiles ---
        f4_t s[2][2];
#pragma unroll
        for (int qt = 0; qt < 2; ++qt)
#pragma unroll
            for (int kt = 0; kt < 2; ++kt) {
                f4_t t = mfma16(kf[kt][0], qf[qt][0], fzero);
                s[qt][kt] = mfma16(kf[kt][1], qf[qt][1], t);
            }

        // --- exp2 + pack + den + P writes (b64, packed) ---
#pragma unroll
        for (int qt = 0; qt < 2; ++qt)
#pragma unroll
            for (int kt = 0; kt < 2; ++kt) {
                bf16x4 pv;
                float d = 0.f;
#pragma unroll
                for (int r = 0; r < 4; ++r) {
                    float p = __builtin_exp2f(s[qt][kt][r]);
                    d += p;
                    pv[r] = (__bf16)p;
                }
                den[qt] += d;
                *(bf16x4*)&P[wave][qt][l15][kt * 16 + quad * 4] = pv;
            }

        // --- PV: A = V^T rows, B = P rows (same-wave LDS, in-order DS) ---
#pragma unroll
        for (int qt = 0; qt < 2; ++qt) {
            bf16x8 pf = *(const bf16x8*)&P[wave][qt][l15][quad * 8];
            racc[0][qt] = mfma16(vf_cur0, pf, racc[0][qt]);
            racc[1][qt] = mfma16(vf_cur1, pf, racc[1][qt]);
        }

        __syncthreads();   // next-buffer K staged; cur free to overwrite
        vf_cur0 = vf_nxt0;
        vf_cur1 = vf_nxt1;
    }

    // den: reduce quad partials (same q = l15 across quads)
#pragma unroll
    for (int qt = 0; qt < 2; ++qt) {
        den[qt] += __shfl_xor(den[qt], 16, 64);
        den[qt] += __shfl_xor(den[qt], 32, 64);
    }

    const size_t pb = (size_t)(nh * KS + ks) * LQ;
    // numPb layout [nh][ks][q][v32] bf16 -- v-contiguous for k3
#pragma unroll
    for (int vt = 0; vt < 2; ++vt)
#pragma unroll
        for (int qt = 0; qt < 2; ++qt) {
            bf16x4 pk;
#pragma unroll
            for (int r = 0; r < 4; ++r) pk[r] = (__bf16)racc[vt][qt][r];
            *(bf16x4*)(numPb + (pb + qbase + qt * 16 + l15) * 32
                             + vt * 16 + quad * 4) = pk;
        }

    if (lane < 16)
#pragma unroll
        for (int qt = 0; qt < 2; ++qt)
            denP[pb + qbase + qt * 16 + lane] = den[qt];
}

// ---------------------------------------------------------------------------
// Kernel 3: vectorized bf16 partial reduce -> R, fp32 projection + residual.
// grid: dim3(256, 2) = l-tile(16) x n = 512 blocks.  block: 256 thr.
// ---------------------------------------------------------------------------
__global__ __launch_bounds__(256) void k3_out(
        const __bf16* __restrict__ numPb, const float* __restrict__ denP,
        const float* __restrict__ Wm, const float* __restrict__ bm,
        const float* __restrict__ x, float* __restrict__ out) {
    const int tid = threadIdx.x;
    const int lt  = blockIdx.x;
    const int n   = blockIdx.y;
    const int l0  = lt * 16;

    __shared__ float Rps[2][64][17];   // [ks-half][j = h*32+v][l]
    __shared__ float dinv[2][16];

    if (tid < 32) {
        const int hh = tid >> 4, li = tid & 15;
        float s = 0.f;
#pragma unroll
        for (int k = 0; k < KS; ++k)
            s += denP[(size_t)((n * 2 + hh) * KS + k) * LQ + l0 + li];
        dinv[hh][li] = 1.0f / s;
    }

    // vectorized reduce over ks (two halves in parallel)
    {
        const int vg = tid & 3, l = (tid >> 2) & 15;
        const int hh = (tid >> 6) & 1, sh = tid >> 7;
        const size_t base = (size_t)(n * 2 + hh) * KS * LQ;
        float a[8] = {0.f, 0.f, 0.f, 0.f, 0.f, 0.f, 0.f, 0.f};
#pragma unroll
        for (int k = 0; k < 4; ++k) {
            const int kk = sh * 4 + k;
            bf16x8 v8 = *(const bf16x8*)(numPb +
                (base + (size_t)kk * LQ + l0 + l) * 32 + vg * 8);
#pragma unroll
            for (int j = 0; j < 8; ++j) a[j] += (float)v8[j];
        }
#pragma unroll
        for (int j = 0; j < 8; ++j)
            Rps[sh][hh * 32 + vg * 8 + j][l] = a[j];
    }
    __syncthreads();

    // projection: thread (l = tid&15, og = tid>>4) -> outputs og*4..+3
    const int l = tid & 15, og = tid >> 4;
    const float d0 = dinv[0][l], d1 = dinv[1][l];
    float rj[64];
#pragma unroll
    for (int j = 0; j < 64; ++j)
        rj[j] = (Rps[0][j][l] + Rps[1][j][l]) * (j < 32 ? d0 : d1);

#pragma unroll
    for (int oi = 0; oi < 4; ++oi) {
        const int o = og * 4 + oi;
        const float* wr = Wm + (size_t)o * 64;
        float a = bm[o];
#pragma unroll
        for (int j4 = 0; j4 < 16; ++j4) {
            f4_t t = *(const f4_t*)(wr + j4 * 4);
            a = fmaf(t[0], rj[j4 * 4 + 0], a);
            a = fmaf(t[1], rj[j4 * 4 + 1], a);
            a = fmaf(t[2], rj[j4 * 4 + 2], a);
            a = fmaf(t[3], rj[j4 * 4 + 3], a);
        }
        const size_t idx = (size_t)(n * 64 + o) * LQ + l0 + l;
        out[idx] = a + x[idx];
    }
}

// ---------------------------------------------------------------------------
extern "C" void kernel_launch(void* const* d_in, const int* in_sizes, int n_in,
                              void* d_out, int out_size, void* d_ws, size_t ws_size,
                              hipStream_t stream) {
    const float* x  = (const float*)d_in[0];
    const float* Wq = (const float*)d_in[1];
    const float* bq = (const float*)d_in[2];
    const float* Wk = (const float*)d_in[3];
    const float* bk = (const float*)d_in[4];
    const float* Wv = (const float*)d_in[5];
    const float* bv = (const float*)d_in[6];
    const float* Wm = (const float*)d_in[7];
    const float* bm = (const float*)d_in[8];
    float* out = (float*)d_out;

    // workspace carve: Qb 2MB | Kb 2MB | Vtb 1MB | numPb 8.4MB | denP 0.5MB
    __bf16* Qb    = (__bf16*)d_ws;
    __bf16* Kb    = Qb + (size_t)NH * LQ * 64;
    __bf16* Vtb   = Kb + (size_t)NH * LQ * 64;
    __bf16* numPb = Vtb + (size_t)NH * 32 * LQ;
    float*  denP  = (float*)(numPb + (size_t)NH * KS * LQ * 32);

    k1_qkv<<<dim3(256, 2), dim3(256), 0, stream>>>(x, Wq, bq, Wk, bk, Wv, bv,
                                                   Qb, Kb, Vtb);
    k2_attn<<<dim3(32, NH, KS), dim3(256), 0, stream>>>(Qb, Kb, Vtb, numPb, denP);
    k3_out<<<dim3(256, 2), dim3(256), 0, stream>>>(numPb, denP, Wm, bm, x, out);
}

// Round 15
// 124.409 us; speedup vs baseline: 1.0130x; 1.0130x over previous
//
#include <hip/hip_runtime.h>
#include <cmath>

// MHSA cosine-attention block, MI355X/gfx950.  Round 15.
// Best-measured recombination:
// K1: R11's 32-l-tile MFMA QKV projection (from the 112.1 us best build).
// K2: R14's flash attention (32-key chunks, K dbuf 8 KB, P 10 KB, V register
//     ping-pong, __launch_bounds__(256,6)) -- measured 44.0 us directly.
// K3: vectorized bf16 partial reduce (R11/R14).

typedef __bf16 bf16x8 __attribute__((ext_vector_type(8)));
typedef __bf16 bf16x4 __attribute__((ext_vector_type(4)));
typedef float f4_t __attribute__((ext_vector_type(4)));

#define LQ 4096       // sequence length H*W
#define NH 4          // n*heads
#define KS 8          // key splits

__device__ inline f4_t mfma16(bf16x8 a, bf16x8 b, f4_t c) {
    return __builtin_amdgcn_mfma_f32_16x16x32_bf16(a, b, c, 0, 0, 0);
}

__device__ inline bf16x8 cvt8(const float* p) {
    f4_t a = *(const f4_t*)p, b = *(const f4_t*)(p + 4);
    bf16x8 r;
    r[0] = (__bf16)a[0]; r[1] = (__bf16)a[1]; r[2] = (__bf16)a[2]; r[3] = (__bf16)a[3];
    r[4] = (__bf16)b[0]; r[5] = (__bf16)b[1]; r[6] = (__bf16)b[2]; r[7] = (__bf16)b[3];
    return r;
}

// ---------------------------------------------------------------------------
// Kernel 1: QKV projection + normalize via MFMA.  (R11)
// grid: dim3(128, 2) = l-tile(32) x n.  block: 256 thr = 4 waves.
// ---------------------------------------------------------------------------
__global__ __launch_bounds__(256) void k1_qkv(
        const float* __restrict__ x,
        const float* __restrict__ Wq, const float* __restrict__ bq,
        const float* __restrict__ Wk, const float* __restrict__ bk,
        const float* __restrict__ Wv, const float* __restrict__ bv,
        __bf16* __restrict__ Qb, __bf16* __restrict__ Kb,
        __bf16* __restrict__ Vtb) {
    const int tid  = threadIdx.x;
    const int lane = tid & 63;
    const int w    = tid >> 6;
    const int quad = lane >> 4;
    const int l15  = lane & 15;
    const int lt   = blockIdx.x;
    const int n    = blockIdx.y;
    const int l0   = lt * 32;

    __shared__ __bf16 xl[32][72];   // [l][c] bf16, pitch 72

    {
        const int c0 = tid >> 5, l = tid & 31;
#pragma unroll
        for (int i = 0; i < 8; ++i) {
            const int c = c0 + i * 8;
            xl[l][c] = (__bf16)x[((size_t)n * 64 + c) * LQ + l0 + l];
        }
    }

    const float* Wqk = (w < 2) ? Wq : Wk;
    const float* bqk = (w < 2) ? bq : bk;
    const int h = w & 1;

    bf16x8 af[4][2], av[2];
#pragma unroll
    for (int t = 0; t < 4; ++t)
#pragma unroll
        for (int kh = 0; kh < 2; ++kh)
            af[t][kh] = cvt8(Wqk + (size_t)(h * 64 + t * 16 + l15) * 64
                                  + kh * 32 + quad * 8);
#pragma unroll
    for (int kh = 0; kh < 2; ++kh)
        av[kh] = cvt8(Wv + (size_t)(w * 16 + l15) * 64 + kh * 32 + quad * 8);

    f4_t binit[4], bvinit;
#pragma unroll
    for (int t = 0; t < 4; ++t)
#pragma unroll
        for (int r = 0; r < 4; ++r)
            binit[t][r] = bqk[h * 64 + t * 16 + quad * 4 + r];
#pragma unroll
    for (int r = 0; r < 4; ++r)
        bvinit[r] = bv[w * 16 + quad * 4 + r];

    __syncthreads();

    f4_t acc[4][2], vacc[2];
#pragma unroll
    for (int lsub = 0; lsub < 2; ++lsub) {
        bf16x8 bf0 = *(const bf16x8*)&xl[lsub * 16 + l15][quad * 8];
        bf16x8 bf1 = *(const bf16x8*)&xl[lsub * 16 + l15][32 + quad * 8];
#pragma unroll
        for (int t = 0; t < 4; ++t) {
            f4_t a = mfma16(af[t][0], bf0, binit[t]);
            acc[t][lsub] = mfma16(af[t][1], bf1, a);
        }
        f4_t va = mfma16(av[0], bf0, bvinit);
        vacc[lsub] = mfma16(av[1], bf1, va);
    }

    const int nh = n * 2 + h;
    __bf16* dst  = (w < 2) ? Qb : Kb;
    const float post = (w < 2) ? 1.44269504f : 1.0f;
#pragma unroll
    for (int lsub = 0; lsub < 2; ++lsub) {
        float ss = 0.f;
#pragma unroll
        for (int t = 0; t < 4; ++t)
#pragma unroll
            for (int r = 0; r < 4; ++r)
                ss = fmaf(acc[t][lsub][r], acc[t][lsub][r], ss);
        ss += __shfl_xor(ss, 16, 64);
        ss += __shfl_xor(ss, 32, 64);
        const float rn = post / fmaxf(sqrtf(ss), 1e-6f);

        const int l = l0 + lsub * 16 + l15;
#pragma unroll
        for (int t = 0; t < 4; ++t) {
            bf16x4 pk;
#pragma unroll
            for (int r = 0; r < 4; ++r) pk[r] = (__bf16)(acc[t][lsub][r] * rn);
            const int kc = t * 2 + (quad >> 1);
            *(bf16x4*)(dst + ((size_t)(nh * 8 + kc) * LQ + l) * 8 + (quad & 1) * 4) = pk;
        }
#pragma unroll
        for (int r = 0; r < 4; ++r) {
            const int vrow = w * 16 + quad * 4 + r;
            Vtb[(size_t)(n * 64 + vrow) * LQ + l] = (__bf16)vacc[lsub][r];
        }
    }
}

// ---------------------------------------------------------------------------
// Kernel 2: flash attention (R14, measured 44.0 us).
// grid: (32 q-blocks of 128, nh=4, ks=8) = 1024 blocks x 4 waves.
// 16 chunks x 32 keys; K dbuf 2x4 KB (shuffled conflict-free map);
// V register ping-pong; P same-wave LDS round trip.  LDS 18 KB +
// launch_bounds(256,6) -> high occupancy.
// ---------------------------------------------------------------------------
__global__ __launch_bounds__(256, 6) void k2_attn(
        const __bf16* __restrict__ Qb, const __bf16* __restrict__ Kb,
        const __bf16* __restrict__ Vtb,
        __bf16* __restrict__ numPb, float* __restrict__ denP) {
    const int tid  = threadIdx.x;
    const int lane = tid & 63;
    const int wave = tid >> 6;
    const int quad = lane >> 4;
    const int l15  = lane & 15;
    const int nh   = blockIdx.y;
    const int ks   = blockIdx.z;
    const int qbase = blockIdx.x * 128 + wave * 32;
    const int kbase = ks * 512;

    __shared__ __bf16 Kl[2][2048];       // 2 x 4 KB staged K chunks (32 keys)
    __shared__ __bf16 P[4][2][16][40];   // [wave][qt][q-row][32 keys + pad]

    const f4_t fzero = {0.f, 0.f, 0.f, 0.f};

    // staging slot map: slot t <-> (kc = ((t>>6)&1)*4 + ((t>>4)&3),
    //                              l  = ((t>>7)<<4)  | (t&15))
    const int s_kc = ((tid >> 6) & 1) * 4 + ((tid >> 4) & 3);
    const int s_l  = ((tid >> 7) << 4) | (tid & 15);
    const __bf16* s_src = Kb + ((size_t)(nh * 8 + s_kc) * LQ + kbase + s_l) * 8;

    // Q fragments (k8-tiled layout), reused for all 512 keys
    bf16x8 qf[2][2];
#pragma unroll
    for (int qt = 0; qt < 2; ++qt)
#pragma unroll
        for (int kh = 0; kh < 2; ++kh)
            qf[qt][kh] = *(const bf16x8*)(Qb +
                ((size_t)(nh * 8 + kh * 4 + quad) * LQ + qbase + qt * 16 + l15) * 8);

    f4_t racc[2][2];                     // [vt][qt]
#pragma unroll
    for (int a = 0; a < 2; ++a)
#pragma unroll
        for (int b = 0; b < 2; ++b) racc[a][b] = fzero;
    float den[2] = {0.f, 0.f};

    // V source base (vt=0; vt=1 adds 16*LQ); chunk ch adds ch*32
    const __bf16* v_src = Vtb + (size_t)(nh * 32 + l15) * LQ + kbase + quad * 8;
    bf16x8 vf_cur0 = *(const bf16x8*)v_src;
    bf16x8 vf_cur1 = *(const bf16x8*)(v_src + (size_t)16 * LQ);

    // stage chunk 0 into buffer 0
    *(bf16x8*)&Kl[0][tid * 8] = *(const bf16x8*)s_src;
    __syncthreads();

#pragma unroll 2
    for (int ch = 0; ch < 16; ++ch) {
        const int cur = ch & 1;

        // prefetch next chunk: K -> LDS (other buffer), V -> registers
        bf16x8 vf_nxt0, vf_nxt1;
        if (ch < 15) {
            *(bf16x8*)&Kl[cur ^ 1][tid * 8] =
                *(const bf16x8*)(s_src + (size_t)(ch + 1) * 256);
            vf_nxt0 = *(const bf16x8*)(v_src + (ch + 1) * 32);
            vf_nxt1 = *(const bf16x8*)(v_src + (size_t)16 * LQ + (ch + 1) * 32);
        }

        // K fragments from staged LDS (contiguous 1 KB per wave-read)
        bf16x8 kf[2][2];
#pragma unroll
        for (int kt = 0; kt < 2; ++kt)
#pragma unroll
            for (int kh = 0; kh < 2; ++kh)
                kf[kt][kh] = *(const bf16x8*)
                    &Kl[cur][(kt * 128 + kh * 64 + quad * 16 + l15) * 8];

        // --- all S^T tiles ---
        f4_t s[2][2];
#pragma unroll
        for (int qt = 0; qt < 2; ++qt)
#pragma unroll
            for (int kt = 0; kt < 2; ++kt) {
                f4_t t = mfma16(kf[kt][0], qf[qt][0], fzero);
                s[qt][kt] = mfma16(kf[kt][1], qf[qt][1], t);
            }

        // --- exp2 + pack + den + P writes (b64, packed) ---
#pragma unroll
        for (int qt = 0; qt < 2; ++qt)
#pragma unroll
            for (int kt = 0; kt < 2; ++kt) {
                bf16x4 pv;
                float d = 0.f;
#pragma unroll
                for (int r = 0; r < 4; ++r) {
                    float p = __builtin_exp2f(s[qt][kt][r]);
                    d += p;
                    pv[r] = (__bf16)p;
                }
                den[qt] += d;
                *(bf16x4*)&P[wave][qt][l15][kt * 16 + quad * 4] = pv;
            }

        // --- PV: A = V^T rows, B = P rows (same-wave LDS, in-order DS) ---
#pragma unroll
        for (int qt = 0; qt < 2; ++qt) {
            bf16x8 pf = *(const bf16x8*)&P[wave][qt][l15][quad * 8];
            racc[0][qt] = mfma16(vf_cur0, pf, racc[0][qt]);
            racc[1][qt] = mfma16(vf_cur1, pf, racc[1][qt]);
        }

        __syncthreads();   // next-buffer K staged; cur free to overwrite
        vf_cur0 = vf_nxt0;
        vf_cur1 = vf_nxt1;
    }

    // den: reduce quad partials (same q = l15 across quads)
#pragma unroll
    for (int qt = 0; qt < 2; ++qt) {
        den[qt] += __shfl_xor(den[qt], 16, 64);
        den[qt] += __shfl_xor(den[qt], 32, 64);
    }

    const size_t pb = (size_t)(nh * KS + ks) * LQ;
    // numPb layout [nh][ks][q][v32] bf16 -- v-contiguous for k3
#pragma unroll
    for (int vt = 0; vt < 2; ++vt)
#pragma unroll
        for (int qt = 0; qt < 2; ++qt) {
            bf16x4 pk;
#pragma unroll
            for (int r = 0; r < 4; ++r) pk[r] = (__bf16)racc[vt][qt][r];
            *(bf16x4*)(numPb + (pb + qbase + qt * 16 + l15) * 32
                             + vt * 16 + quad * 4) = pk;
        }

    if (lane < 16)
#pragma unroll
        for (int qt = 0; qt < 2; ++qt)
            denP[pb + qbase + qt * 16 + lane] = den[qt];
}

// ---------------------------------------------------------------------------
// Kernel 3: vectorized bf16 partial reduce -> R, fp32 projection + residual.
// grid: dim3(256, 2) = l-tile(16) x n = 512 blocks.  block: 256 thr.
// ---------------------------------------------------------------------------
__global__ __launch_bounds__(256) void k3_out(
        const __bf16* __restrict__ numPb, const float* __restrict__ denP,
        const float* __restrict__ Wm, const float* __restrict__ bm,
        const float* __restrict__ x, float* __restrict__ out) {
    const int tid = threadIdx.x;
    const int lt  = blockIdx.x;
    const int n   = blockIdx.y;
    const int l0  = lt * 16;

    __shared__ float Rps[2][64][17];   // [ks-half][j = h*32+v][l]
    __shared__ float dinv[2][16];

    if (tid < 32) {
        const int hh = tid >> 4, li = tid & 15;
        float s = 0.f;
#pragma unroll
        for (int k = 0; k < KS; ++k)
            s += denP[(size_t)((n * 2 + hh) * KS + k) * LQ + l0 + li];
        dinv[hh][li] = 1.0f / s;
    }

    // vectorized reduce over ks (two halves in parallel)
    {
        const int vg = tid & 3, l = (tid >> 2) & 15;
        const int hh = (tid >> 6) & 1, sh = tid >> 7;
        const size_t base = (size_t)(n * 2 + hh) * KS * LQ;
        float a[8] = {0.f, 0.f, 0.f, 0.f, 0.f, 0.f, 0.f, 0.f};
#pragma unroll
        for (int k = 0; k < 4; ++k) {
            const int kk = sh * 4 + k;
            bf16x8 v8 = *(const bf16x8*)(numPb +
                (base + (size_t)kk * LQ + l0 + l) * 32 + vg * 8);
#pragma unroll
            for (int j = 0; j < 8; ++j) a[j] += (float)v8[j];
        }
#pragma unroll
        for (int j = 0; j < 8; ++j)
            Rps[sh][hh * 32 + vg * 8 + j][l] = a[j];
    }
    __syncthreads();

    // projection: thread (l = tid&15, og = tid>>4) -> outputs og*4..+3
    const int l = tid & 15, og = tid >> 4;
    const float d0 = dinv[0][l], d1 = dinv[1][l];
    float rj[64];
#pragma unroll
    for (int j = 0; j < 64; ++j)
        rj[j] = (Rps[0][j][l] + Rps[1][j][l]) * (j < 32 ? d0 : d1);

#pragma unroll
    for (int oi = 0; oi < 4; ++oi) {
        const int o = og * 4 + oi;
        const float* wr = Wm + (size_t)o * 64;
        float a = bm[o];
#pragma unroll
        for (int j4 = 0; j4 < 16; ++j4) {
            f4_t t = *(const f4_t*)(wr + j4 * 4);
            a = fmaf(t[0], rj[j4 * 4 + 0], a);
            a = fmaf(t[1], rj[j4 * 4 + 1], a);
            a = fmaf(t[2], rj[j4 * 4 + 2], a);
            a = fmaf(t[3], rj[j4 * 4 + 3], a);
        }
        const size_t idx = (size_t)(n * 64 + o) * LQ + l0 + l;
        out[idx] = a + x[idx];
    }
}

// ---------------------------------------------------------------------------
extern "C" void kernel_launch(void* const* d_in, const int* in_sizes, int n_in,
                              void* d_out, int out_size, void* d_ws, size_t ws_size,
                              hipStream_t stream) {
    const float* x  = (const float*)d_in[0];
    const float* Wq = (const float*)d_in[1];
    const float* bq = (const float*)d_in[2];
    const float* Wk = (const float*)d_in[3];
    const float* bk = (const float*)d_in[4];
    const float* Wv = (const float*)d_in[5];
    const float* bv = (const float*)d_in[6];
    const float* Wm = (const float*)d_in[7];
    const float* bm = (const float*)d_in[8];
    float* out = (float*)d_out;

    // workspace carve: Qb 2MB | Kb 2MB | Vtb 1MB | numPb 8.4MB | denP 0.5MB
    __bf16* Qb    = (__bf16*)d_ws;
    __bf16* Kb    = Qb + (size_t)NH * LQ * 64;
    __bf16* Vtb   = Kb + (size_t)NH * LQ * 64;
    __bf16* numPb = Vtb + (size_t)NH * 32 * LQ;
    float*  denP  = (float*)(numPb + (size_t)NH * KS * LQ * 32);

    k1_qkv<<<dim3(128, 2), dim3(256), 0, stream>>>(x, Wq, bq, Wk, bk, Wv, bv,
                                                   Qb, Kb, Vtb);
    k2_attn<<<dim3(32, NH, KS), dim3(256), 0, stream>>>(Qb, Kb, Vtb, numPb, denP);
    k3_out<<<dim3(256, 2), dim3(256), 0, stream>>>(numPb, denP, Wm, bm, x, out);
}